// Round 8
// baseline (413.616 us; speedup 1.0000x reference)
//
#include <hip/hip_runtime.h>
#include <hip/hip_bf16.h>
#include <stdint.h>

typedef __hip_bfloat16 bf16;
typedef __attribute__((ext_vector_type(8))) short short8;
typedef __attribute__((ext_vector_type(4))) short short4v;
typedef __attribute__((ext_vector_type(4))) float floatx4;

#define E_DIM 1024
#define S_LEN 2048
#define NB    2
#define NH    16
#define HD    64
#define FFN   4096
#define MTOT  4096   // NB * S_LEN

#define LOG2E 1.4426950408889634f
#define QSCALE (0.125f * LOG2E)

// ---- async global->LDS, 16B per lane (wave-uniform LDS base + lane*16) ----
__device__ __forceinline__ void gl_lds16(const void* g, void* l) {
  __builtin_amdgcn_global_load_lds(
      (__attribute__((address_space(1))) void*)(g),
      (__attribute__((address_space(3))) void*)(l), 16, 0, 0);
}

// LDS chunk swizzles (chunk = 16B = 8 bf16; 8 chunks per 64-elem row)
__device__ __forceinline__ int fswz_v(int row) { return row & 7; }
__device__ __forceinline__ int fswz_k(int row) {
  return ((row ^ (row >> 3)) & 3) | ((((row >> 3) ^ (row >> 4)) & 1) << 2);
}

__device__ __forceinline__ float bf16bits2float(short s) {
  union { unsigned u; float f; } c;
  c.u = ((unsigned)(unsigned short)s) << 16;
  return c.f;
}

// ---------------------------------------------------------------------------
// fp32 -> bf16 convert (4 elems/thread)
// ---------------------------------------------------------------------------
__global__ __launch_bounds__(256)
void cvt_bf16(const float* __restrict__ in, bf16* __restrict__ out) {
  const size_t i = ((size_t)blockIdx.x * 256 + threadIdx.x) * 4;
  float4 v = *(const float4*)(in + i);
  out[i + 0] = __float2bfloat16(v.x);
  out[i + 1] = __float2bfloat16(v.y);
  out[i + 2] = __float2bfloat16(v.z);
  out[i + 3] = __float2bfloat16(v.w);
}

// ---------------------------------------------------------------------------
// All weight transposes in one kernel: 12 z-slices of 1024x1024 blocks.
// ---------------------------------------------------------------------------
__global__ __launch_bounds__(256)
void transpose_all(const float* __restrict__ wq, const float* __restrict__ wk,
                   const float* __restrict__ wv, const float* __restrict__ wo,
                   const float* __restrict__ f1, const float* __restrict__ f2,
                   bf16* __restrict__ W3T, bf16* __restrict__ woT,
                   bf16* __restrict__ f1T, bf16* __restrict__ f2T) {
  const int z = blockIdx.z;
  const float* in;
  bf16* out;
  int inStride, outStride, rOff, cOff;
  if (z < 4) {
    in = (z == 0) ? wq : (z == 1) ? wk : (z == 2) ? wv : wo;
    out = (z < 3) ? (W3T + (size_t)z * 1024 * 1024) : woT;
    inStride = 1024; outStride = 1024; rOff = 0; cOff = 0;
  } else if (z < 8) {
    in = f1; out = f1T; inStride = 4096; outStride = 1024;
    rOff = 0; cOff = (z - 4) * 1024;
  } else {
    in = f2; out = f2T; inStride = 1024; outStride = 4096;
    rOff = (z - 8) * 1024; cOff = 0;
  }
  __shared__ float tile[32][33];
  const int tx = threadIdx.x & 31;
  const int ty = threadIdx.x >> 5;
  const int c0 = blockIdx.x * 32;
  const int r0 = blockIdx.y * 32;
#pragma unroll
  for (int j = 0; j < 32; j += 8)
    tile[ty + j][tx] =
        in[(size_t)(rOff + r0 + ty + j) * inStride + cOff + c0 + tx];
  __syncthreads();
#pragma unroll
  for (int j = 0; j < 32; j += 8)
    out[(size_t)(cOff + c0 + ty + j) * outStride + rOff + r0 + tx] =
        __float2bfloat16(tile[tx][ty + j]);
}

// concat biases (Q bias pre-scaled by 0.125*log2e)
__global__ __launch_bounds__(256)
void prep_bias(const float* __restrict__ qb, const float* __restrict__ kb,
               const float* __restrict__ vb, float* __restrict__ out) {
  const int i = blockIdx.x * 256 + threadIdx.x;
  float v = (i < 1024) ? qb[i] * QSCALE
                       : ((i < 2048) ? kb[i - 1024] : vb[i - 2048]);
  out[i] = v;
}

// ---------------------------------------------------------------------------
// GEMM: C(M,N) = A(M,K) @ B^T, B stored (N,K) row-major, both bf16.
// 128x128 tile, BK=32, 4 waves x (64x64), 16x16x32 bf16 MFMA (m97 structure).
// Split-K via gridDim.z; lda = full row stride of A and B.
// mode 0: fp32 store, no bias, output offset z*M*N (split-K partial)
// mode 1: ReLU + bf16 row-major store (+bias)
// mode 2: fused-QKV scatter. N=3072; col>>10 selects Q/K/V.
//         Q scaled 0.125*log2e (bias pre-scaled), Q/K -> (B*H,S,D), V -> (B*H,D,S).
// ---------------------------------------------------------------------------
__global__ __launch_bounds__(256)
void gemm_bt(const bf16* __restrict__ A, const bf16* __restrict__ B,
             const float* __restrict__ bias, void* __restrict__ Cout,
             int M, int N, int Kpart, int lda, int mode) {
  __shared__ alignas(16) bf16 sA[128 * 32];
  __shared__ alignas(16) bf16 sB[128 * 32];
  const int tid   = threadIdx.x;
  const int wave  = tid >> 6;
  const int lane  = tid & 63;
  const int row16 = lane & 15;
  const int quad  = lane >> 4;
  const int m0 = blockIdx.x * 128;
  const int n0 = blockIdx.y * 128;
  const int wm = (wave >> 1) * 64;
  const int wn = (wave & 1) * 64;
  const int koff = blockIdx.z * Kpart;

  floatx4 acc[4][4];
#pragma unroll
  for (int i = 0; i < 4; i++)
#pragma unroll
    for (int j = 0; j < 4; j++) {
      floatx4 z = {0.f, 0.f, 0.f, 0.f};
      acc[i][j] = z;
    }

  for (int k0 = koff; k0 < koff + Kpart; k0 += 32) {
#pragma unroll
    for (int j = 0; j < 2; ++j) {
      const int chunk = wave * 2 + j;
      const int e = chunk * 512 + lane * 8;
      const int r = e >> 5;
      const int kk = e & 31;
      gl_lds16(A + (size_t)(m0 + r) * lda + k0 + kk, sA + chunk * 512);
      gl_lds16(B + (size_t)(n0 + r) * lda + k0 + kk, sB + chunk * 512);
    }
    __syncthreads();

    short8 af[4], bfr[4];
#pragma unroll
    for (int i = 0; i < 4; i++) {
      af[i]  = *(const short8*)(sA + (wm + i * 16 + row16) * 32 + quad * 8);
      bfr[i] = *(const short8*)(sB + (wn + i * 16 + row16) * 32 + quad * 8);
    }
#pragma unroll
    for (int mi = 0; mi < 4; mi++)
#pragma unroll
      for (int ni = 0; ni < 4; ni++)
        acc[mi][ni] = __builtin_amdgcn_mfma_f32_16x16x32_bf16(
            af[mi], bfr[ni], acc[mi][ni], 0, 0, 0);
    __syncthreads();
  }

  float bval[4] = {0.f, 0.f, 0.f, 0.f};
  if (mode != 0) {
#pragma unroll
    for (int ni = 0; ni < 4; ni++) bval[ni] = bias[n0 + wn + ni * 16 + row16];
  }

#pragma unroll
  for (int mi = 0; mi < 4; mi++) {
#pragma unroll
    for (int ni = 0; ni < 4; ni++) {
      const int col = n0 + wn + ni * 16 + row16;
      if (mode == 0) {
        float* co = (float*)Cout + (size_t)blockIdx.z * M * N;
#pragma unroll
        for (int r = 0; r < 4; r++) {
          const int row = m0 + wm + mi * 16 + quad * 4 + r;
          co[(size_t)row * N + col] = acc[mi][ni][r];
        }
      } else if (mode == 1) {
#pragma unroll
        for (int r = 0; r < 4; r++) {
          const int row = m0 + wm + mi * 16 + quad * 4 + r;
          float v = acc[mi][ni][r] + bval[ni];
          v = v > 0.f ? v : 0.f;
          ((bf16*)Cout)[(size_t)row * N + col] = __float2bfloat16(v);
        }
      } else {
        // fused QKV scatter
        const int mat = col >> 10;
        const int c10 = col & 1023;
        const int hh = c10 >> 6, dd = c10 & 63;
        const float scl = (mat == 0) ? QSCALE : 1.0f;
        bf16* qout = (bf16*)Cout;
        const int rbase = m0 + wm + mi * 16 + quad * 4;
        const int b = rbase >> 11, s = rbase & 2047;
        const size_t bh = (size_t)b * NH + hh;
        if (mat == 2) {
          bf16* vt = qout + (1 << 23);
          short4v pv;
#pragma unroll
          for (int r = 0; r < 4; r++) {
            bf16 t = __float2bfloat16(acc[mi][ni][r] + bval[ni]);
            pv[r] = *(short*)&t;
          }
          *(short4v*)(vt + (bh * HD + dd) * S_LEN + s) = pv;
        } else {
          bf16* o = (mat == 1) ? (qout + (1 << 22)) : qout;
#pragma unroll
          for (int r = 0; r < 4; r++) {
            float v = acc[mi][ni][r] * scl + bval[ni];
            o[(bh * S_LEN + s + r) * HD + dd] = __float2bfloat16(v);
          }
        }
      }
    }
  }
}

// ---------------------------------------------------------------------------
// Flash attention v5: KT=64, exp2 softmax, LDS double-buffer with
// POST-barrier prefetch (1 barrier/tile; staging latency hidden by compute).
// Q,K: (B*H,S,D) bf16 (Q pre-scaled 0.125*log2e); Vt: (B*H,D,S) bf16.
// Out: (B,S,E) bf16, heads merged. sigma key permutation makes QK^T C-layout
// == PV B-operand layout (no P transform).
// ---------------------------------------------------------------------------
__global__ __launch_bounds__(256, 4)
void flash_attn(const bf16* __restrict__ Q, const bf16* __restrict__ K,
                const bf16* __restrict__ Vt, const float* __restrict__ mask,
                bf16* __restrict__ Out) {
  __shared__ alignas(16) bf16 sK[2][64 * 64];  // [key][d], swizzled fswz_k
  __shared__ alignas(16) bf16 sV[2][64 * 64];  // [d][key], swizzled fswz_v
  __shared__ alignas(16) float sM[S_LEN];      // -1e12*log2e * mask[b][*]

  const int tid   = threadIdx.x;
  const int wave  = tid >> 6;
  const int lane  = tid & 63;
  const int row16 = lane & 15;
  const int quad  = lane >> 4;
  const int bh = blockIdx.y;
  const int b = bh >> 4, h = bh & 15;
  const int q0 = blockIdx.x * 64;
  const int qg = q0 + wave * 16 + row16;

  const bf16* qp = Q + ((size_t)bh * S_LEN + qg) * HD;
  short8 qf0 = *(const short8*)(qp + quad * 8);
  short8 qf1 = *(const short8*)(qp + 32 + quad * 8);

  const bf16* Kbase = K + (size_t)bh * S_LEN * HD;
  const bf16* Vbase = Vt + (size_t)bh * HD * S_LEN;

  // per-wave staging of one K/V tile into buffer `buf`
  const int srow = (lane >> 3);
  const int scp  = lane & 7;
#define STAGE(kt, buf)                                                        \
  {                                                                           \
    const bf16* Kg_ = Kbase + (size_t)(kt)*64 * HD;                           \
    const bf16* Vg_ = Vbase + (kt)*64;                                        \
    _Pragma("unroll") for (int j = 0; j < 2; ++j) {                           \
      const int ch = wave * 2 + j;                                            \
      const int row = ch * 8 + srow;                                          \
      gl_lds16(Kg_ + row * 64 + ((scp ^ fswz_k(row)) * 8), sK[buf] + ch*512); \
      gl_lds16(Vg_ + (size_t)row * S_LEN + ((scp ^ fswz_v(row)) * 8),         \
               sV[buf] + ch * 512);                                           \
    }                                                                         \
  }

  STAGE(0, 0)

  for (int i = tid; i < S_LEN / 4; i += 256) {
    float4 mv = ((const float4*)(mask + (size_t)b * S_LEN))[i];
    const float c = -1e12f * LOG2E;
    float4 w = {c * mv.x, c * mv.y, c * mv.z, c * mv.w};
    ((float4*)sM)[i] = w;
  }

  float m_i = -1e30f, l_i = 0.f;
  floatx4 ov[4];
#pragma unroll
  for (int i = 0; i < 4; i++) { floatx4 z = {0.f,0.f,0.f,0.f}; ov[i] = z; }

  int cur = 0;
  for (int kt = 0; kt < S_LEN / 64; ++kt) {
    __syncthreads();   // drains tile-kt gl_lds (issued after previous barrier)
    if (kt + 1 < S_LEN / 64) STAGE(kt + 1, cur ^ 1)

    const bf16* sKc = sK[cur];
    const bf16* sVc = sV[cur];

    // scores: 4 tiles of 16 keys; key(mi,r)=kt*64+quad*8+(mi&1)*4+r+(mi>>1)*32
    floatx4 sc[4];
#pragma unroll
    for (int mi = 0; mi < 4; mi++) {
      const int row = ((row16 >> 2) << 3) + (row16 & 3) + ((mi & 1) << 2) + ((mi >> 1) << 5);
      const int fk = fswz_k(row);
      short8 kf0 = *(const short8*)(sKc + row * 64 + ((quad ^ fk) << 3));
      short8 kf1 = *(const short8*)(sKc + row * 64 + (((4 + quad) ^ fk) << 3));
      floatx4 z = {0.f, 0.f, 0.f, 0.f};
      z = __builtin_amdgcn_mfma_f32_16x16x32_bf16(kf0, qf0, z, 0, 0, 0);
      sc[mi] = __builtin_amdgcn_mfma_f32_16x16x32_bf16(kf1, qf1, z, 0, 0, 0);
    }

    // mask add (vector)
#pragma unroll
    for (int mi = 0; mi < 4; mi++) {
      float4 mv = *(const float4*)(sM + kt * 64 + (quad << 3) + ((mi & 1) << 2) + ((mi >> 1) << 5));
      floatx4 m4 = {mv.x, mv.y, mv.z, mv.w};
      sc[mi] += m4;
    }

    // online softmax (base-2)
    floatx4 mx4 = sc[0];
#pragma unroll
    for (int mi = 1; mi < 4; mi++) {
      mx4[0] = fmaxf(mx4[0], sc[mi][0]);
      mx4[1] = fmaxf(mx4[1], sc[mi][1]);
      mx4[2] = fmaxf(mx4[2], sc[mi][2]);
      mx4[3] = fmaxf(mx4[3], sc[mi][3]);
    }
    float t = fmaxf(fmaxf(mx4[0], mx4[1]), fmaxf(mx4[2], mx4[3]));
    t = fmaxf(t, __shfl_xor(t, 16));
    t = fmaxf(t, __shfl_xor(t, 32));
    const float m_new = fmaxf(m_i, t);
    const float alpha = __builtin_exp2f(m_i - m_new);
    m_i = m_new;

    floatx4 nm4 = {-m_new, -m_new, -m_new, -m_new};
    floatx4 s4 = {0.f, 0.f, 0.f, 0.f};
#pragma unroll
    for (int mi = 0; mi < 4; mi++) {
      floatx4 a = sc[mi] + nm4;
      a[0] = __builtin_exp2f(a[0]);
      a[1] = __builtin_exp2f(a[1]);
      a[2] = __builtin_exp2f(a[2]);
      a[3] = __builtin_exp2f(a[3]);
      sc[mi] = a;
      s4 += a;
    }
    float tsum = (s4[0] + s4[1]) + (s4[2] + s4[3]);
    tsum += __shfl_xor(tsum, 16);
    tsum += __shfl_xor(tsum, 32);
    l_i = l_i * alpha + tsum;

    // pack P into PV B-operand fragments (in-lane)
    short8 pf[2];
#pragma unroll
    for (int ks = 0; ks < 2; ks++)
#pragma unroll
      for (int jp = 0; jp < 4; jp++) {
        const int mi = 2 * ks + (jp >> 1);
        const int r0 = (jp & 1) * 2;
        bf16 p0 = __float2bfloat16(sc[mi][r0]);
        bf16 p1 = __float2bfloat16(sc[mi][r0 + 1]);
        pf[ks][2 * jp]     = *(short*)&p0;
        pf[ks][2 * jp + 1] = *(short*)&p1;
      }

    // rescale O, then O^T += V^T . P
    floatx4 al4 = {alpha, alpha, alpha, alpha};
#pragma unroll
    for (int mi = 0; mi < 4; mi++) ov[mi] *= al4;
#pragma unroll
    for (int mi = 0; mi < 4; mi++) {
      const int row = mi * 16 + row16;
      const int fv = fswz_v(row);
      short8 v0 = *(const short8*)(sVc + row * 64 + ((quad ^ fv) << 3));
      short8 v1 = *(const short8*)(sVc + row * 64 + (((4 + quad) ^ fv) << 3));
      ov[mi] = __builtin_amdgcn_mfma_f32_16x16x32_bf16(v0, pf[0], ov[mi], 0, 0, 0);
      ov[mi] = __builtin_amdgcn_mfma_f32_16x16x32_bf16(v1, pf[1], ov[mi], 0, 0, 0);
    }
    cur ^= 1;
  }
#undef STAGE

  const float inv = 1.0f / l_i;
#pragma unroll
  for (int mi = 0; mi < 4; mi++) {
    short4v pv;
#pragma unroll
    for (int r = 0; r < 4; r++) {
      bf16 t = __float2bfloat16(ov[mi][r] * inv);
      pv[r] = *(short*)&t;
    }
    *(short4v*)(Out + ((size_t)(b * S_LEN + qg)) * E_DIM + h * HD + mi * 16 + quad * 4) = pv;
  }
}

// ---------------------------------------------------------------------------
// Split-K reduce + residual + bias + LayerNorm, one block per row.
// ---------------------------------------------------------------------------
__global__ __launch_bounds__(256)
void ln_reduce(const float* __restrict__ p0, const float* __restrict__ p1,
               const float* __restrict__ resf, const bf16* __restrict__ resb,
               const float* __restrict__ bias, const float* __restrict__ g,
               const float* __restrict__ be, float* __restrict__ outf,
               bf16* __restrict__ outb) {
  const int row = blockIdx.x;
  const int tid = threadIdx.x;
  const size_t base = (size_t)row * 1024;
  const int c = tid * 4;
  float4 a = *(const float4*)(p0 + base + c);
  float4 bq = *(const float4*)(p1 + base + c);
  float4 rv;
  if (resf) {
    rv = *(const float4*)(resf + base + c);
  } else {
    short4v rb = *(const short4v*)((const short*)resb + base + c);
    rv.x = bf16bits2float(rb[0]);
    rv.y = bf16bits2float(rb[1]);
    rv.z = bf16bits2float(rb[2]);
    rv.w = bf16bits2float(rb[3]);
  }
  float4 bi = *(const float4*)(bias + c);
  float4 xv;
  xv.x = a.x + bq.x + rv.x + bi.x;
  xv.y = a.y + bq.y + rv.y + bi.y;
  xv.z = a.z + bq.z + rv.z + bi.z;
  xv.w = a.w + bq.w + rv.w + bi.w;
  float s  = xv.x + xv.y + xv.z + xv.w;
  float s2 = xv.x * xv.x + xv.y * xv.y + xv.z * xv.z + xv.w * xv.w;
#pragma unroll
  for (int d = 1; d < 64; d <<= 1) {
    s  += __shfl_xor(s, d);
    s2 += __shfl_xor(s2, d);
  }
  __shared__ float red[2][4];
  const int wave = tid >> 6;
  if ((tid & 63) == 0) { red[0][wave] = s; red[1][wave] = s2; }
  __syncthreads();
  s  = red[0][0] + red[0][1] + red[0][2] + red[0][3];
  s2 = red[1][0] + red[1][1] + red[1][2] + red[1][3];
  const float mu  = s * (1.0f / 1024.0f);
  const float var = s2 * (1.0f / 1024.0f) - mu * mu;
  const float rs  = rsqrtf(var + 1e-9f);
  float4 gg = *(const float4*)(g + c);
  float4 bb = *(const float4*)(be + c);
  float4 y;
  y.x = (xv.x - mu) * rs * gg.x + bb.x;
  y.y = (xv.y - mu) * rs * gg.y + bb.y;
  y.z = (xv.z - mu) * rs * gg.z + bb.z;
  y.w = (xv.w - mu) * rs * gg.w + bb.w;
  if (outf) *(float4*)(outf + base + c) = y;
  if (outb) {
    bf16* o = outb + base + c;
    o[0] = __float2bfloat16(y.x);
    o[1] = __float2bfloat16(y.y);
    o[2] = __float2bfloat16(y.z);
    o[3] = __float2bfloat16(y.w);
  }
}

// ---------------------------------------------------------------------------
extern "C" void kernel_launch(void* const* d_in, const int* in_sizes, int n_in,
                              void* d_out, int out_size, void* d_ws,
                              size_t ws_size, hipStream_t stream) {
  const float* x    = (const float*)d_in[0];
  const float* mask = (const float*)d_in[1];
  const float* wq_w = (const float*)d_in[2];
  const float* wq_b = (const float*)d_in[3];
  const float* wk_w = (const float*)d_in[4];
  const float* wk_b = (const float*)d_in[5];
  const float* wv_w = (const float*)d_in[6];
  const float* wv_b = (const float*)d_in[7];
  const float* wo_w = (const float*)d_in[8];
  const float* wo_b = (const float*)d_in[9];
  const float* f1_w = (const float*)d_in[10];
  const float* f1_b = (const float*)d_in[11];
  const float* f2_w = (const float*)d_in[12];
  const float* f2_b = (const float*)d_in[13];
  const float* ln1_g = (const float*)d_in[14];
  const float* ln1_b = (const float*)d_in[15];
  const float* ln2_g = (const float*)d_in[16];
  const float* ln2_b = (const float*)d_in[17];
  float* out = (float*)d_out;

  char* ws = (char*)d_ws;
  const size_t MB = 1u << 20;
  bf16*  xbf   = (bf16*)(ws + 0 * MB);
  bf16*  W3T   = (bf16*)(ws + 8 * MB);
  bf16*  woT   = (bf16*)(ws + 14 * MB);
  float* bqkv  = (float*)(ws + 16 * MB);
  bf16*  Qb    = (bf16*)(ws + 17 * MB);
  bf16*  attnb = (bf16*)(ws + 0 * MB);
  bf16*  ffn1  = (bf16*)(ws + 17 * MB);
  bf16*  f1T   = (bf16*)(ws + 49 * MB);
  bf16*  f2T   = (bf16*)(ws + 57 * MB);
  float* parts = (float*)(ws + 65 * MB);   // 2 x 16 MB (proj, then f2)
  bf16*  hbf   = (bf16*)(ws + 97 * MB);
  const size_t PSTRIDE = (size_t)MTOT * E_DIM;

  // pre-pass
  cvt_bf16<<<4096, 256, 0, stream>>>(x, xbf);
  transpose_all<<<dim3(32, 32, 12), 256, 0, stream>>>(
      wq_w, wk_w, wv_w, wo_w, f1_w, f2_w, W3T, woT, f1T, f2T);
  prep_bias<<<12, 256, 0, stream>>>(wq_b, wk_b, wv_b, bqkv);

  // fused QKV projection -> Qb (B*H,S,D), Kb, Vt (B*H,D,S)
  gemm_bt<<<dim3(32, 24, 1), 256, 0, stream>>>(xbf, W3T, bqkv, Qb,
                                               MTOT, 3 * E_DIM, E_DIM, E_DIM, 2);

  // attention
  flash_attn<<<dim3(S_LEN / 64, NB * NH), 256, 0, stream>>>(
      Qb, Qb + (1 << 22), Qb + (1 << 23), mask, attnb);

  // output projection, split-K=2 -> fp32 partials
  gemm_bt<<<dim3(32, 8, 2), 256, 0, stream>>>(attnb, woT, nullptr, parts,
                                              MTOT, E_DIM, E_DIM / 2, E_DIM, 0);

  // h = LN(p0+p1+wo_b + x) -> bf16 only
  ln_reduce<<<MTOT, 256, 0, stream>>>(parts, parts + PSTRIDE, x, nullptr,
                                      wo_b, ln1_g, ln1_b, nullptr, hbf);

  // FFN1: relu(h @ f1 + b) -> bf16
  gemm_bt<<<dim3(32, 32, 1), 256, 0, stream>>>(hbf, f1T, f1_b, ffn1,
                                               MTOT, FFN, E_DIM, E_DIM, 1);

  // FFN2, split-K=2 -> fp32 partials
  gemm_bt<<<dim3(32, 8, 2), 256, 0, stream>>>(ffn1, f2T, nullptr, parts,
                                              MTOT, E_DIM, FFN / 2, FFN, 0);

  // out = LN(p0+p1+f2_b + h)
  ln_reduce<<<MTOT, 256, 0, stream>>>(parts, parts + PSTRIDE, nullptr, hbf,
                                      f2_b, ln2_g, ln2_b, out, nullptr);
}

// Round 9
// 395.008 us; speedup vs baseline: 1.0471x; 1.0471x over previous
//
#include <hip/hip_runtime.h>
#include <hip/hip_bf16.h>
#include <stdint.h>

typedef __hip_bfloat16 bf16;
typedef __attribute__((ext_vector_type(8))) short short8;
typedef __attribute__((ext_vector_type(4))) short short4v;
typedef __attribute__((ext_vector_type(4))) float floatx4;

#define E_DIM 1024
#define S_LEN 2048
#define NB    2
#define NH    16
#define HD    64
#define FFN   4096
#define MTOT  4096   // NB * S_LEN

#define LOG2E 1.4426950408889634f
#define QSCALE (0.125f * LOG2E)

// ---- async global->LDS, 16B per lane (wave-uniform LDS base + lane*16) ----
__device__ __forceinline__ void gl_lds16(const void* g, void* l) {
  __builtin_amdgcn_global_load_lds(
      (__attribute__((address_space(1))) void*)(g),
      (__attribute__((address_space(3))) void*)(l), 16, 0, 0);
}

// LDS chunk swizzles (chunk = 16B = 8 bf16; 8 chunks per 64-elem row)
__device__ __forceinline__ int fswz_v(int row) { return row & 7; }
__device__ __forceinline__ int fswz_k(int row) {
  return ((row ^ (row >> 3)) & 3) | ((((row >> 3) ^ (row >> 4)) & 1) << 2);
}

__device__ __forceinline__ float bf16bits2float(short s) {
  union { unsigned u; float f; } c;
  c.u = ((unsigned)(unsigned short)s) << 16;
  return c.f;
}

// ---------------------------------------------------------------------------
// fp32 -> bf16 convert (4 elems/thread)
// ---------------------------------------------------------------------------
__global__ __launch_bounds__(256)
void cvt_bf16(const float* __restrict__ in, bf16* __restrict__ out) {
  const size_t i = ((size_t)blockIdx.x * 256 + threadIdx.x) * 4;
  float4 v = *(const float4*)(in + i);
  out[i + 0] = __float2bfloat16(v.x);
  out[i + 1] = __float2bfloat16(v.y);
  out[i + 2] = __float2bfloat16(v.z);
  out[i + 3] = __float2bfloat16(v.w);
}

// ---------------------------------------------------------------------------
// All weight transposes in one kernel: 12 z-slices of 1024x1024 blocks.
// ---------------------------------------------------------------------------
__global__ __launch_bounds__(256)
void transpose_all(const float* __restrict__ wq, const float* __restrict__ wk,
                   const float* __restrict__ wv, const float* __restrict__ wo,
                   const float* __restrict__ f1, const float* __restrict__ f2,
                   bf16* __restrict__ W3T, bf16* __restrict__ woT,
                   bf16* __restrict__ f1T, bf16* __restrict__ f2T) {
  const int z = blockIdx.z;
  const float* in;
  bf16* out;
  int inStride, outStride, rOff, cOff;
  if (z < 4) {
    in = (z == 0) ? wq : (z == 1) ? wk : (z == 2) ? wv : wo;
    out = (z < 3) ? (W3T + (size_t)z * 1024 * 1024) : woT;
    inStride = 1024; outStride = 1024; rOff = 0; cOff = 0;
  } else if (z < 8) {
    in = f1; out = f1T; inStride = 4096; outStride = 1024;
    rOff = 0; cOff = (z - 4) * 1024;
  } else {
    in = f2; out = f2T; inStride = 1024; outStride = 4096;
    rOff = (z - 8) * 1024; cOff = 0;
  }
  __shared__ float tile[32][33];
  const int tx = threadIdx.x & 31;
  const int ty = threadIdx.x >> 5;
  const int c0 = blockIdx.x * 32;
  const int r0 = blockIdx.y * 32;
#pragma unroll
  for (int j = 0; j < 32; j += 8)
    tile[ty + j][tx] =
        in[(size_t)(rOff + r0 + ty + j) * inStride + cOff + c0 + tx];
  __syncthreads();
#pragma unroll
  for (int j = 0; j < 32; j += 8)
    out[(size_t)(cOff + c0 + ty + j) * outStride + rOff + r0 + tx] =
        __float2bfloat16(tile[tx][ty + j]);
}

// concat biases (Q bias pre-scaled by 0.125*log2e)
__global__ __launch_bounds__(256)
void prep_bias(const float* __restrict__ qb, const float* __restrict__ kb,
               const float* __restrict__ vb, float* __restrict__ out) {
  const int i = blockIdx.x * 256 + threadIdx.x;
  float v = (i < 1024) ? qb[i] * QSCALE
                       : ((i < 2048) ? kb[i - 1024] : vb[i - 2048]);
  out[i] = v;
}

// ---------------------------------------------------------------------------
// GEMM: C(M,N) = A(M,K) @ B^T, B stored (N,K) row-major, both bf16.
// 128x128 tile, BK=32, 4 waves x (64x64), 16x16x32 bf16 MFMA (m97 structure).
// Split-K via gridDim.z; lda = full row stride of A and B.
// mode 0: fp32 store, no bias, output offset z*M*N (split-K partial)
// mode 1: ReLU + bf16 row-major store (+bias)
// mode 2: fused-QKV scatter. N=3072; col>>10 selects Q/K/V.
//         Q scaled 0.125*log2e (bias pre-scaled), Q/K -> (B*H,S,D), V -> (B*H,D,S).
// ---------------------------------------------------------------------------
__global__ __launch_bounds__(256)
void gemm_bt(const bf16* __restrict__ A, const bf16* __restrict__ B,
             const float* __restrict__ bias, void* __restrict__ Cout,
             int M, int N, int Kpart, int lda, int mode) {
  __shared__ alignas(16) bf16 sA[128 * 32];
  __shared__ alignas(16) bf16 sB[128 * 32];
  const int tid   = threadIdx.x;
  const int wave  = tid >> 6;
  const int lane  = tid & 63;
  const int row16 = lane & 15;
  const int quad  = lane >> 4;
  const int m0 = blockIdx.x * 128;
  const int n0 = blockIdx.y * 128;
  const int wm = (wave >> 1) * 64;
  const int wn = (wave & 1) * 64;
  const int koff = blockIdx.z * Kpart;

  floatx4 acc[4][4];
#pragma unroll
  for (int i = 0; i < 4; i++)
#pragma unroll
    for (int j = 0; j < 4; j++) {
      floatx4 z = {0.f, 0.f, 0.f, 0.f};
      acc[i][j] = z;
    }

  for (int k0 = koff; k0 < koff + Kpart; k0 += 32) {
#pragma unroll
    for (int j = 0; j < 2; ++j) {
      const int chunk = wave * 2 + j;
      const int e = chunk * 512 + lane * 8;
      const int r = e >> 5;
      const int kk = e & 31;
      gl_lds16(A + (size_t)(m0 + r) * lda + k0 + kk, sA + chunk * 512);
      gl_lds16(B + (size_t)(n0 + r) * lda + k0 + kk, sB + chunk * 512);
    }
    __syncthreads();

    short8 af[4], bfr[4];
#pragma unroll
    for (int i = 0; i < 4; i++) {
      af[i]  = *(const short8*)(sA + (wm + i * 16 + row16) * 32 + quad * 8);
      bfr[i] = *(const short8*)(sB + (wn + i * 16 + row16) * 32 + quad * 8);
    }
#pragma unroll
    for (int mi = 0; mi < 4; mi++)
#pragma unroll
      for (int ni = 0; ni < 4; ni++)
        acc[mi][ni] = __builtin_amdgcn_mfma_f32_16x16x32_bf16(
            af[mi], bfr[ni], acc[mi][ni], 0, 0, 0);
    __syncthreads();
  }

  float bval[4] = {0.f, 0.f, 0.f, 0.f};
  if (mode != 0) {
#pragma unroll
    for (int ni = 0; ni < 4; ni++) bval[ni] = bias[n0 + wn + ni * 16 + row16];
  }

#pragma unroll
  for (int mi = 0; mi < 4; mi++) {
#pragma unroll
    for (int ni = 0; ni < 4; ni++) {
      const int col = n0 + wn + ni * 16 + row16;
      if (mode == 0) {
        float* co = (float*)Cout + (size_t)blockIdx.z * M * N;
#pragma unroll
        for (int r = 0; r < 4; r++) {
          const int row = m0 + wm + mi * 16 + quad * 4 + r;
          co[(size_t)row * N + col] = acc[mi][ni][r];
        }
      } else if (mode == 1) {
#pragma unroll
        for (int r = 0; r < 4; r++) {
          const int row = m0 + wm + mi * 16 + quad * 4 + r;
          float v = acc[mi][ni][r] + bval[ni];
          v = v > 0.f ? v : 0.f;
          ((bf16*)Cout)[(size_t)row * N + col] = __float2bfloat16(v);
        }
      } else {
        // fused QKV scatter
        const int mat = col >> 10;
        const int c10 = col & 1023;
        const int hh = c10 >> 6, dd = c10 & 63;
        const float scl = (mat == 0) ? QSCALE : 1.0f;
        bf16* qout = (bf16*)Cout;
        const int rbase = m0 + wm + mi * 16 + quad * 4;
        const int b = rbase >> 11, s = rbase & 2047;
        const size_t bh = (size_t)b * NH + hh;
        if (mat == 2) {
          bf16* vt = qout + (1 << 23);
          short4v pv;
#pragma unroll
          for (int r = 0; r < 4; r++) {
            bf16 t = __float2bfloat16(acc[mi][ni][r] + bval[ni]);
            pv[r] = *(short*)&t;
          }
          *(short4v*)(vt + (bh * HD + dd) * S_LEN + s) = pv;
        } else {
          bf16* o = (mat == 1) ? (qout + (1 << 22)) : qout;
#pragma unroll
          for (int r = 0; r < 4; r++) {
            float v = acc[mi][ni][r] * scl + bval[ni];
            o[(bh * S_LEN + s + r) * HD + dd] = __float2bfloat16(v);
          }
        }
      }
    }
  }
}

// ---------------------------------------------------------------------------
// Flash attention v6: R4 single-buffer structure + native v_exp_f32 softmax
// (log2e pre-folded) + XCD-friendly grid: blockIdx.x = bh (fastest dim), so
// round-robin block->XCD dispatch gives each XCD a ~4-head K/V working set
// (~2 MB < 4 MB L2) reused across all 32 q-tiles.
// Q,K: (B*H,S,D) bf16 (Q pre-scaled 0.125*log2e); Vt: (B*H,D,S) bf16.
// Out: (B,S,E) bf16, heads merged. sigma key permutation makes QK^T C-layout
// == PV B-operand layout (no P transform).
// ---------------------------------------------------------------------------
__global__ __launch_bounds__(256, 4)
void flash_attn(const bf16* __restrict__ Q, const bf16* __restrict__ K,
                const bf16* __restrict__ Vt, const float* __restrict__ mask,
                bf16* __restrict__ Out) {
  __shared__ alignas(16) bf16 sK[64 * 64];   // [key][d], chunk-swizzled fswz_k
  __shared__ alignas(16) bf16 sV[64 * 64];   // [d][key], chunk-swizzled fswz_v
  __shared__ alignas(16) float sM[S_LEN];    // -1e12*log2e * mask[b][*]

  const int tid   = threadIdx.x;
  const int wave  = tid >> 6;
  const int lane  = tid & 63;
  const int row16 = lane & 15;
  const int quad  = lane >> 4;
  const int bh = blockIdx.x;               // fastest dim -> XCD locality
  const int b = bh >> 4, h = bh & 15;
  const int q0 = blockIdx.y * 64;
  const int qg = q0 + wave * 16 + row16;

  const bf16* qp = Q + ((size_t)bh * S_LEN + qg) * HD;
  short8 qf0 = *(const short8*)(qp + quad * 8);
  short8 qf1 = *(const short8*)(qp + 32 + quad * 8);

  for (int i = tid; i < S_LEN / 4; i += 256) {
    float4 mv = ((const float4*)(mask + (size_t)b * S_LEN))[i];
    const float c = -1e12f * LOG2E;
    float4 w = {c * mv.x, c * mv.y, c * mv.z, c * mv.w};
    ((float4*)sM)[i] = w;
  }

  float m_i = -1e30f, l_i = 0.f;
  floatx4 ov[4];
#pragma unroll
  for (int i = 0; i < 4; i++) { floatx4 z = {0.f,0.f,0.f,0.f}; ov[i] = z; }

  const bf16* Kbase = K + (size_t)bh * S_LEN * HD;
  const bf16* Vbase = Vt + (size_t)bh * HD * S_LEN;

  for (int kt = 0; kt < S_LEN / 64; ++kt) {
    const bf16* Kg = Kbase + (size_t)kt * 64 * HD;
    const bf16* Vg = Vbase + kt * 64;
#pragma unroll
    for (int j = 0; j < 2; ++j) {
      const int ch = wave * 2 + j;
      const int row = ch * 8 + (lane >> 3);
      const int sc_ = lane & 7;
      gl_lds16(Kg + row * 64 + ((sc_ ^ fswz_k(row)) * 8), sK + ch * 512);
      gl_lds16(Vg + (size_t)row * S_LEN + ((sc_ ^ fswz_v(row)) * 8), sV + ch * 512);
    }
    __syncthreads();

    // scores: 4 tiles of 16 keys; key(mi,r)=kt*64+quad*8+(mi&1)*4+r+(mi>>1)*32
    floatx4 sc[4];
#pragma unroll
    for (int mi = 0; mi < 4; mi++) {
      const int row = ((row16 >> 2) << 3) + (row16 & 3) + ((mi & 1) << 2) + ((mi >> 1) << 5);
      const int fk = fswz_k(row);
      short8 kf0 = *(const short8*)(sK + row * 64 + ((quad ^ fk) << 3));
      short8 kf1 = *(const short8*)(sK + row * 64 + (((4 + quad) ^ fk) << 3));
      floatx4 z = {0.f, 0.f, 0.f, 0.f};
      z = __builtin_amdgcn_mfma_f32_16x16x32_bf16(kf0, qf0, z, 0, 0, 0);
      sc[mi] = __builtin_amdgcn_mfma_f32_16x16x32_bf16(kf1, qf1, z, 0, 0, 0);
    }

    // mask add (vector)
#pragma unroll
    for (int mi = 0; mi < 4; mi++) {
      float4 mv = *(const float4*)(sM + kt * 64 + (quad << 3) + ((mi & 1) << 2) + ((mi >> 1) << 5));
      floatx4 m4 = {mv.x, mv.y, mv.z, mv.w};
      sc[mi] += m4;
    }

    // online softmax (base-2, native v_exp_f32)
    floatx4 mx4 = sc[0];
#pragma unroll
    for (int mi = 1; mi < 4; mi++) {
      mx4[0] = fmaxf(mx4[0], sc[mi][0]);
      mx4[1] = fmaxf(mx4[1], sc[mi][1]);
      mx4[2] = fmaxf(mx4[2], sc[mi][2]);
      mx4[3] = fmaxf(mx4[3], sc[mi][3]);
    }
    float t = fmaxf(fmaxf(mx4[0], mx4[1]), fmaxf(mx4[2], mx4[3]));
    t = fmaxf(t, __shfl_xor(t, 16));
    t = fmaxf(t, __shfl_xor(t, 32));
    const float m_new = fmaxf(m_i, t);
    const float alpha = __builtin_amdgcn_exp2f(m_i - m_new);
    m_i = m_new;

    floatx4 nm4 = {-m_new, -m_new, -m_new, -m_new};
    floatx4 s4 = {0.f, 0.f, 0.f, 0.f};
#pragma unroll
    for (int mi = 0; mi < 4; mi++) {
      floatx4 a = sc[mi] + nm4;
      a[0] = __builtin_amdgcn_exp2f(a[0]);
      a[1] = __builtin_amdgcn_exp2f(a[1]);
      a[2] = __builtin_amdgcn_exp2f(a[2]);
      a[3] = __builtin_amdgcn_exp2f(a[3]);
      sc[mi] = a;
      s4 += a;
    }
    float tsum = (s4[0] + s4[1]) + (s4[2] + s4[3]);
    tsum += __shfl_xor(tsum, 16);
    tsum += __shfl_xor(tsum, 32);
    l_i = l_i * alpha + tsum;

    // pack P into PV B-operand fragments (in-lane)
    short8 pf[2];
#pragma unroll
    for (int ks = 0; ks < 2; ks++)
#pragma unroll
      for (int jp = 0; jp < 4; jp++) {
        const int mi = 2 * ks + (jp >> 1);
        const int r0 = (jp & 1) * 2;
        bf16 p0 = __float2bfloat16(sc[mi][r0]);
        bf16 p1 = __float2bfloat16(sc[mi][r0 + 1]);
        pf[ks][2 * jp]     = *(short*)&p0;
        pf[ks][2 * jp + 1] = *(short*)&p1;
      }

    // rescale O, then O^T += V^T . P
    floatx4 al4 = {alpha, alpha, alpha, alpha};
#pragma unroll
    for (int mi = 0; mi < 4; mi++) ov[mi] *= al4;
#pragma unroll
    for (int mi = 0; mi < 4; mi++) {
      const int row = mi * 16 + row16;
      const int fv = fswz_v(row);
      short8 v0 = *(const short8*)(sV + row * 64 + ((quad ^ fv) << 3));
      short8 v1 = *(const short8*)(sV + row * 64 + (((4 + quad) ^ fv) << 3));
      ov[mi] = __builtin_amdgcn_mfma_f32_16x16x32_bf16(v0, pf[0], ov[mi], 0, 0, 0);
      ov[mi] = __builtin_amdgcn_mfma_f32_16x16x32_bf16(v1, pf[1], ov[mi], 0, 0, 0);
    }
    __syncthreads();
  }

  const float inv = 1.0f / l_i;
#pragma unroll
  for (int mi = 0; mi < 4; mi++) {
    short4v pv;
#pragma unroll
    for (int r = 0; r < 4; r++) {
      bf16 t = __float2bfloat16(ov[mi][r] * inv);
      pv[r] = *(short*)&t;
    }
    *(short4v*)(Out + ((size_t)(b * S_LEN + qg)) * E_DIM + h * HD + mi * 16 + quad * 4) = pv;
  }
}

// ---------------------------------------------------------------------------
// Split-K reduce + residual + bias + LayerNorm, one block per row.
// ---------------------------------------------------------------------------
__global__ __launch_bounds__(256)
void ln_reduce(const float* __restrict__ p0, const float* __restrict__ p1,
               const float* __restrict__ resf, const bf16* __restrict__ resb,
               const float* __restrict__ bias, const float* __restrict__ g,
               const float* __restrict__ be, float* __restrict__ outf,
               bf16* __restrict__ outb) {
  const int row = blockIdx.x;
  const int tid = threadIdx.x;
  const size_t base = (size_t)row * 1024;
  const int c = tid * 4;
  float4 a = *(const float4*)(p0 + base + c);
  float4 bq = *(const float4*)(p1 + base + c);
  float4 rv;
  if (resf) {
    rv = *(const float4*)(resf + base + c);
  } else {
    short4v rb = *(const short4v*)((const short*)resb + base + c);
    rv.x = bf16bits2float(rb[0]);
    rv.y = bf16bits2float(rb[1]);
    rv.z = bf16bits2float(rb[2]);
    rv.w = bf16bits2float(rb[3]);
  }
  float4 bi = *(const float4*)(bias + c);
  float4 xv;
  xv.x = a.x + bq.x + rv.x + bi.x;
  xv.y = a.y + bq.y + rv.y + bi.y;
  xv.z = a.z + bq.z + rv.z + bi.z;
  xv.w = a.w + bq.w + rv.w + bi.w;
  float s  = xv.x + xv.y + xv.z + xv.w;
  float s2 = xv.x * xv.x + xv.y * xv.y + xv.z * xv.z + xv.w * xv.w;
#pragma unroll
  for (int d = 1; d < 64; d <<= 1) {
    s  += __shfl_xor(s, d);
    s2 += __shfl_xor(s2, d);
  }
  __shared__ float red[2][4];
  const int wave = tid >> 6;
  if ((tid & 63) == 0) { red[0][wave] = s; red[1][wave] = s2; }
  __syncthreads();
  s  = red[0][0] + red[0][1] + red[0][2] + red[0][3];
  s2 = red[1][0] + red[1][1] + red[1][2] + red[1][3];
  const float mu  = s * (1.0f / 1024.0f);
  const float var = s2 * (1.0f / 1024.0f) - mu * mu;
  const float rs  = rsqrtf(var + 1e-9f);
  float4 gg = *(const float4*)(g + c);
  float4 bb = *(const float4*)(be + c);
  float4 y;
  y.x = (xv.x - mu) * rs * gg.x + bb.x;
  y.y = (xv.y - mu) * rs * gg.y + bb.y;
  y.z = (xv.z - mu) * rs * gg.z + bb.z;
  y.w = (xv.w - mu) * rs * gg.w + bb.w;
  if (outf) *(float4*)(outf + base + c) = y;
  if (outb) {
    bf16* o = outb + base + c;
    o[0] = __float2bfloat16(y.x);
    o[1] = __float2bfloat16(y.y);
    o[2] = __float2bfloat16(y.z);
    o[3] = __float2bfloat16(y.w);
  }
}

// ---------------------------------------------------------------------------
extern "C" void kernel_launch(void* const* d_in, const int* in_sizes, int n_in,
                              void* d_out, int out_size, void* d_ws,
                              size_t ws_size, hipStream_t stream) {
  const float* x    = (const float*)d_in[0];
  const float* mask = (const float*)d_in[1];
  const float* wq_w = (const float*)d_in[2];
  const float* wq_b = (const float*)d_in[3];
  const float* wk_w = (const float*)d_in[4];
  const float* wk_b = (const float*)d_in[5];
  const float* wv_w = (const float*)d_in[6];
  const float* wv_b = (const float*)d_in[7];
  const float* wo_w = (const float*)d_in[8];
  const float* wo_b = (const float*)d_in[9];
  const float* f1_w = (const float*)d_in[10];
  const float* f1_b = (const float*)d_in[11];
  const float* f2_w = (const float*)d_in[12];
  const float* f2_b = (const float*)d_in[13];
  const float* ln1_g = (const float*)d_in[14];
  const float* ln1_b = (const float*)d_in[15];
  const float* ln2_g = (const float*)d_in[16];
  const float* ln2_b = (const float*)d_in[17];
  float* out = (float*)d_out;

  char* ws = (char*)d_ws;
  const size_t MB = 1u << 20;
  bf16*  xbf   = (bf16*)(ws + 0 * MB);
  bf16*  W3T   = (bf16*)(ws + 8 * MB);
  bf16*  woT   = (bf16*)(ws + 14 * MB);
  float* bqkv  = (float*)(ws + 16 * MB);
  bf16*  Qb    = (bf16*)(ws + 17 * MB);
  bf16*  attnb = (bf16*)(ws + 0 * MB);
  bf16*  ffn1  = (bf16*)(ws + 17 * MB);
  bf16*  f1T   = (bf16*)(ws + 49 * MB);
  bf16*  f2T   = (bf16*)(ws + 57 * MB);
  float* parts = (float*)(ws + 65 * MB);   // 2 x 16 MB (proj, then f2)
  bf16*  hbf   = (bf16*)(ws + 97 * MB);
  const size_t PSTRIDE = (size_t)MTOT * E_DIM;

  // pre-pass
  cvt_bf16<<<4096, 256, 0, stream>>>(x, xbf);
  transpose_all<<<dim3(32, 32, 12), 256, 0, stream>>>(
      wq_w, wk_w, wv_w, wo_w, f1_w, f2_w, W3T, woT, f1T, f2T);
  prep_bias<<<12, 256, 0, stream>>>(wq_b, wk_b, wv_b, bqkv);

  // fused QKV projection -> Qb (B*H,S,D), Kb, Vt (B*H,D,S)
  gemm_bt<<<dim3(32, 24, 1), 256, 0, stream>>>(xbf, W3T, bqkv, Qb,
                                               MTOT, 3 * E_DIM, E_DIM, E_DIM, 2);

  // attention (grid: x = bh for XCD L2 locality, y = q-tile)
  flash_attn<<<dim3(NB * NH, S_LEN / 64), 256, 0, stream>>>(
      Qb, Qb + (1 << 22), Qb + (1 << 23), mask, attnb);

  // output projection, split-K=2 -> fp32 partials
  gemm_bt<<<dim3(32, 8, 2), 256, 0, stream>>>(attnb, woT, nullptr, parts,
                                              MTOT, E_DIM, E_DIM / 2, E_DIM, 0);

  // h = LN(p0+p1+wo_b + x) -> bf16 only
  ln_reduce<<<MTOT, 256, 0, stream>>>(parts, parts + PSTRIDE, x, nullptr,
                                      wo_b, ln1_g, ln1_b, nullptr, hbf);

  // FFN1: relu(h @ f1 + b) -> bf16
  gemm_bt<<<dim3(32, 32, 1), 256, 0, stream>>>(hbf, f1T, f1_b, ffn1,
                                               MTOT, FFN, E_DIM, E_DIM, 1);

  // FFN2, split-K=2 -> fp32 partials
  gemm_bt<<<dim3(32, 8, 2), 256, 0, stream>>>(ffn1, f2T, nullptr, parts,
                                              MTOT, E_DIM, FFN / 2, FFN, 0);

  // out = LN(p0+p1+f2_b + h)
  ln_reduce<<<MTOT, 256, 0, stream>>>(parts, parts + PSTRIDE, nullptr, hbf,
                                      f2_b, ln2_g, ln2_b, out, nullptr);
}